// Round 14
// baseline (154.544 us; speedup 1.0000x reference)
//
#include <hip/hip_runtime.h>

typedef unsigned long long u64;
typedef unsigned int u32;
typedef unsigned short u16;
typedef unsigned char u8;

#define VOX 0.4f
#define GAM 1.1f
#define NCX 16        // 16x16 cells
#define CELLW 32.0f   // voxels per cell (power of 2: floor(pvx/32) exact)
#define CAP 64        // max candidate boxes per cell (sentinel fallback if exceeded)

// IEEE f32, no contraction: replicate numpy/jax op-for-op.
__device__ __forceinline__ float dist2d(float ax, float ay, float bx, float by) {
  float dx = __fsub_rn(ax, bx);
  float dy = __fsub_rn(ay, by);
  return __fsqrt_rn(__fadd_rn(__fmul_rn(dx, dx), __fmul_rn(dy, dy)));
}

// metric radius = norm(dims*0.5) * GAMMA
__device__ __forceinline__ float box_radius(const float* __restrict__ boxes, int m) {
  float hx = __fmul_rn(boxes[m * 7 + 3], 0.5f);
  float hy = __fmul_rn(boxes[m * 7 + 4], 0.5f);
  float nr = __fsqrt_rn(__fadd_rn(__fmul_rn(hx, hx), __fmul_rn(hy, hy)));
  return __fmul_rn(nr, GAM);
}

// voxel-space box transform (shared so values are identical everywhere)
__device__ __forceinline__ void box_voxel(const float* __restrict__ boxes, int m,
                                          float psx, float psy,
                                          float& qx, float& qy, float& r) {
  qx = __fdiv_rn(__fsub_rn(boxes[m * 7 + 0], psx), VOX);
  qy = __fdiv_rn(__fsub_rn(boxes[m * 7 + 1], psy), VOX);
  float hx = __fmul_rn(boxes[m * 7 + 3], 0.5f);
  float hy = __fmul_rn(boxes[m * 7 + 4], 0.5f);
  float nr = __fsqrt_rn(__fadd_rn(__fmul_rn(hx, hx), __fmul_rn(hy, hy)));
  r = __fdiv_rn(__fmul_rn(nr, GAM), VOX);
}

// ---- merged prep: block 0 -> voxel box arrays; blocks 1.. -> cell candidate lists
__global__ void k_prep(const float* __restrict__ boxes, const float* __restrict__ pc_start,
                       float* __restrict__ qxv, float* __restrict__ qyv, float* __restrict__ rv,
                       int* __restrict__ cellCnt, u16* __restrict__ cellList, int M) {
  const int tid = threadIdx.x;
  if (blockIdx.x == 0) {
    for (int m = tid; m < M; m += 256) {
      float qx, qy, r;
      box_voxel(boxes, m, pc_start[0], pc_start[1], qx, qy, r);
      qxv[m] = qx; qyv[m] = qy; rv[m] = r;
    }
    return;
  }
  const int cell = blockIdx.x - 1;
  const int cx = cell & (NCX - 1), cy = cell >> 4;
  const int wv = tid >> 6, lane = tid & 63;
  __shared__ int wcnt[4];
  const float x0 = (cx == 0) ? -3e38f : cx * CELLW;
  const float x1 = (cx == NCX - 1) ? 3e38f : (cx + 1) * CELLW;
  const float y0 = (cy == 0) ? -3e38f : cy * CELLW;
  const float y1 = (cy == NCX - 1) ? 3e38f : (cy + 1) * CELLW;
  bool hit = false;
  if (tid < M) {
    float qx, qy, r;
    box_voxel(boxes, tid, pc_start[0], pc_start[1], qx, qy, r);
    float ddx = fmaxf(0.0f, fmaxf(x0 - qx, qx - x1));
    float ddy = fmaxf(0.0f, fmaxf(y0 - qy, qy - y1));
    float rr = r + 0.01f;  // conservative margin >> f32 rounding of exact test chain
    hit = (ddx * ddx + ddy * ddy <= rr * rr);
  }
  u64 b = __ballot(hit);
  if (lane == 0) wcnt[wv] = __popcll(b);
  __syncthreads();
  int base = 0;
  for (int w = 0; w < wv; ++w) base += wcnt[w];
  if (hit) {
    int slot = base + __popcll(b & ((1ULL << lane) - 1ULL));
    if (slot < CAP) cellList[cell * CAP + slot] = (u16)tid;  // ascending m
  }
  if (tid == 0) cellCnt[cell] = wcnt[0] + wcnt[1] + wcnt[2] + wcnt[3];
}

// ---- fused: binned vmask (strict <) + ORDERED compaction + per-(chunk,box) match
//      BITMAP via point-centric candidate tests. chunk == one block == 256 points.
//      bmG layout: [chunk][m][4] -> coalesced dump writes.
__global__ void k_vmask_count(const float* __restrict__ pts, const float* __restrict__ boxes,
                              const float* __restrict__ qxv, const float* __restrict__ qyv,
                              const float* __restrict__ rv,
                              const int* __restrict__ cellCnt, const u16* __restrict__ cellList,
                              u64* __restrict__ vbits, u8* __restrict__ present,
                              u64* __restrict__ bmG, int* __restrict__ cpng,
                              const float* __restrict__ pc_start,
                              int N, int M) {
  __shared__ float cpx[256], cpy[256];          // compacted flagged points (metric xy)
  __shared__ int cpn[256];                      // compacted point indices
  __shared__ int ccell[256];                    // compacted point cell ids
  __shared__ float sbx[256], sby[256], sbr[256];// metric box centers/radii
  __shared__ u64 bm[256][4];                    // per-box match bitmap over 256 slots
  __shared__ int wcnt[4];
  const int tid = threadIdx.x;
  const int blk = blockIdx.x;
  const int n = blk * 256 + tid;
  const int wv = tid >> 6, lane = tid & 63;
  const float psx = pc_start[0], psy = pc_start[1];
  const bool valid = (n < N);

  bm[tid][0] = 0; bm[tid][1] = 0; bm[tid][2] = 0; bm[tid][3] = 0;
  if (tid < M) {
    sbx[tid] = boxes[tid * 7 + 0];
    sby[tid] = boxes[tid * 7 + 1];
    sbr[tid] = box_radius(boxes, tid);
  }

  float px = 1e6f, py = 1e6f, pvx = 0.f, pvy = 0.f;
  if (valid) {
    px = pts[n * 5 + 0];
    py = pts[n * 5 + 1];
    pvx = __fdiv_rn(__fsub_rn(px, psx), VOX);
    pvy = __fdiv_rn(__fsub_rn(py, psy), VOX);
    present[n] = 0;
  }

  // pass 1: vmask via candidate cells; identical IEEE ops as full loop
  bool flag = false;
  int mycell = 0;
  if (valid) {
    int cx = (int)floorf(pvx * (1.0f / CELLW));  // exact: /32 power of two
    int cy = (int)floorf(pvy * (1.0f / CELLW));
    cx = cx < 0 ? 0 : (cx > NCX - 1 ? NCX - 1 : cx);
    cy = cy < 0 ? 0 : (cy > NCX - 1 ? NCX - 1 : cy);
    mycell = cy * NCX + cx;
    const int k = cellCnt[mycell];
    if (k <= CAP) {
      for (int j = 0; j < k; ++j) {
        const int m = cellList[mycell * CAP + j];
        float d = dist2d(qxv[m], qyv[m], pvx, pvy);
        if (d < rv[m]) { flag = true; break; }  // strict <
      }
    } else {  // sentinel fallback (dormant for this data)
      for (int m = 0; m < M; ++m) {
        float d = dist2d(qxv[m], qyv[m], pvx, pvy);
        if (d < rv[m]) { flag = true; break; }
      }
    }
  }
  u64 b = __ballot(flag);
  if (lane == 0) {
    vbits[n >> 6] = b;
    wcnt[wv] = __popcll(b);
  }
  __syncthreads();

  // ORDERED compaction (ascending n) of flagged points into LDS
  int base = 0;
  for (int w = 0; w < wv; ++w) base += wcnt[w];
  if (flag) {
    int slot = base + __popcll(b & ((1ULL << lane) - 1ULL));
    cpx[slot] = px;
    cpy[slot] = py;
    cpn[slot] = n;
    ccell[slot] = mycell;
  }
  __syncthreads();
  const int nfl = wcnt[0] + wcnt[1] + wcnt[2] + wcnt[3];
  if (tid < nfl) cpng[blk * 256 + tid] = cpn[tid];

  // pass 2: point-centric metric tests against the point's cell candidates.
  // Exact: metric match d<=r implies voxel dist <= rv + ~1e-4 << 0.01 margin,
  // so the candidate list provably contains every metric-matching box.
  if (tid < nfl) {
    const float mx = cpx[tid], my = cpy[tid];
    const int cell = ccell[tid];
    const int k = cellCnt[cell];
    const u64 bit = 1ULL << (tid & 63);
    const int word = tid >> 6;
    if (k <= CAP) {
      for (int j = 0; j < k; ++j) {
        const int m = cellList[cell * CAP + j];
        float d = dist2d(sbx[m], sby[m], mx, my);
        if (d <= sbr[m]) atomicOr(&bm[m][word], bit);  // metric space, <= (LDS atomic)
      }
    } else {  // fallback: test all boxes (dormant)
      for (int m = 0; m < M; ++m) {
        float d = dist2d(sbx[m], sby[m], mx, my);
        if (d <= sbr[m]) atomicOr(&bm[m][word], bit);
      }
    }
  }
  __syncthreads();

  // dump bitmap (thread = box; [chunk][m] layout -> coalesced 8KB block write)
  if (tid < M) {
    u64* dst = bmG + ((size_t)blk * M + tid) * 4;
    dst[0] = bm[tid][0]; dst[1] = bm[tid][1];
    dst[2] = bm[tid][2]; dst[3] = bm[tid][3];
  }
}

// ---- fused per-box scan + bitmap fill + wide zero-fill. block = box, 1024 thr ----
__global__ void __launch_bounds__(1024) k_scanfill(
    const float* __restrict__ pts, const float* __restrict__ boxes,
    const u64* __restrict__ bmG, const int* __restrict__ cpng,
    const u64* __restrict__ vbits, int* __restrict__ kcount,
    int* __restrict__ sidx, u8* __restrict__ present,
    int N, int M, int S, int nchunk) {
  const int m = blockIdx.x;
  const int t = threadIdx.x;
  const int lane = t & 63, wv = t >> 6;  // 16 waves
  __shared__ int wsum[16];
  __shared__ int zws[16];

  // load my chunk's bitmap (thread t = chunk t; nchunk <= 1024)
  u64 w0 = 0, w1 = 0, w2 = 0, w3 = 0;
  int v = 0;
  if (t < nchunk) {
    const u64* bp = bmG + ((size_t)t * M + m) * 4;
    w0 = bp[0]; w1 = bp[1]; w2 = bp[2]; w3 = bp[3];
    v = __popcll(w0) + __popcll(w1) + __popcll(w2) + __popcll(w3);
  }
  // inclusive wave-shfl scan
  int incl = v;
  for (int d = 1; d < 64; d <<= 1) {
    int x = __shfl_up(incl, d);
    if (lane >= d) incl += x;
  }
  if (lane == 63) wsum[wv] = incl;
  __syncthreads();
  if (t < 16) {  // scan the 16 wave sums (lanes 0-15 of wave 0)
    int s = wsum[t];
    for (int d = 1; d < 16; d <<= 1) {
      int x = __shfl_up(s, d);
      if (t >= d) s += x;
    }
    wsum[t] = s;  // inclusive
  }
  __syncthreads();
  const int wbase = (wv > 0) ? wsum[wv - 1] : 0;
  const int off = wbase + incl - v;  // exclusive prefix over chunks
  const int total = wsum[15];
  const int k0 = total < S ? total : S;
  if (t == 0) kcount[m] = k0;

  // fill from bitmap (ascending slot = ascending point index); plain byte stores
  if (t < nchunk && v > 0 && off < S) {
    const int* pbase = cpng + t * 256;
    int cum = off;
    u64 ws4[4] = {w0, w1, w2, w3};
    for (int wi = 0; wi < 4 && cum < S; ++wi) {
      u64 w = ws4[wi];
      while (w && cum < S) {
        int j = (wi << 6) + __builtin_ctzll(w);
        w &= w - 1;
        int pn = pbase[j];
        sidx[m * S + cum] = pn;
        present[pn] = 1;   // idempotent byte store (no atomic contention)
        ++cum;
      }
    }
  }

  // zero-fill: lowest-index non-matches (top_k tie-break among zeros)
  if (k0 >= S) return;  // uniform per block -> barrier-safe
  const float bx = boxes[m * 7 + 0], by = boxes[m * 7 + 1];
  const float r = box_radius(boxes, m);
  const u64 ltmask = (1ULL << lane) - 1ULL;
  int fill = k0;
  for (int p0 = 0; p0 < N && fill < S; p0 += 1024) {
    const int n = p0 + t;
    const bool validn = n < N;
    bool one = false;
    if (validn) {
      u64 wbit = vbits[n >> 6];  // one word per wave (broadcast)
      if ((wbit >> (n & 63)) & 1ULL) {
        float d = dist2d(bx, by, pts[n * 5 + 0], pts[n * 5 + 1]);
        one = (d <= r);
      }
    }
    const bool z = validn && !one;
    u64 b = __ballot(z);
    if (lane == 0) zws[wv] = __popcll(b);
    __syncthreads();
    int zbase = 0, ztot = 0;
    for (int ww = 0; ww < 16; ++ww) {
      int c = zws[ww];
      if (ww < wv) zbase += c;
      ztot += c;
    }
    if (z) {
      int pos = fill + zbase + __popcll(b & ltmask);
      if (pos < S) { sidx[m * S + pos] = n; present[n] = 1; }
    }
    fill += ztot;
    __syncthreads();
  }
}

// --- fused output kernel: per-block LDS pbits rebuild + replicated scan + outputs.
//     32 blocks x 1024 threads; each block redundantly builds the 25KB presence
//     bitmap + per-chunk exclusive offsets in LDS, then emits its 1024 elements.
#define NW64 3200  // max u64 words (nchunk*4 <= 3128 for N=200000; padded)
__global__ void __launch_bounds__(1024) k_out(
    const float* __restrict__ pts, const int* __restrict__ sidx,
    const int* __restrict__ kcount, const u8* __restrict__ present,
    float* __restrict__ out_samp, float* __restrict__ out_idx,
    float* __restrict__ out_query, int N, int MS, int S, int nchunk) {
  __shared__ u64 shp[NW64];     // presence bitmap
  __shared__ int shb[1024];     // per-chunk exclusive offsets
  __shared__ int wsum[16];
  const int t = threadIdx.x, lane = t & 63, wv = t >> 6;
  const int nw = nchunk * 4;    // u64 words covering N (incl. tail)

  // phase 1: build pbits in LDS via wave ballot (coalesced 64B reads/wave)
  for (int i = wv; i < nw; i += 16) {
    const int n = i * 64 + lane;
    const bool f = (n < N) && present[n];
    u64 b = __ballot(f);
    if (lane == 0) shp[i] = b;
  }
  __syncthreads();

  // phase 2: per-chunk counts + replicated 2-level shfl exclusive scan
  int v = 0;
  if (t < nchunk) {
    const u64* p = &shp[t * 4];
    v = __popcll(p[0]) + __popcll(p[1]) + __popcll(p[2]) + __popcll(p[3]);
  }
  int incl = v;
  for (int d = 1; d < 64; d <<= 1) {
    int x = __shfl_up(incl, d);
    if (lane >= d) incl += x;
  }
  if (lane == 63) wsum[wv] = incl;
  __syncthreads();
  if (t < 16) {
    int s = wsum[t];
    for (int d = 1; d < 16; d <<= 1) {
      int x = __shfl_up(s, d);
      if (t >= d) s += x;
    }
    wsum[t] = s;
  }
  __syncthreads();
  shb[t] = ((wv > 0) ? wsum[wv - 1] : 0) + incl - v;  // exclusive
  const int U = wsum[15];
  __syncthreads();

  // phase 3: outputs (sampled + idx with inline rank) + query rows + padding
  const int e = blockIdx.x * 1024 + t;
  if (e >= MS) return;
  if (e >= U) {  // pad query rows with points[0] (unique fill_value=0)
    float* q = out_query + (size_t)e * 5;
    q[0] = pts[0]; q[1] = pts[1]; q[2] = pts[2]; q[3] = pts[3]; q[4] = pts[4];
  }
  const int m = e / S;
  const int s = e - m * S;
  const int n = sidx[e];  // valid for ALL slots (fill or zero-fill wrote it)
  // rank(n) = shb[chunk] + popcount of presence bits below n (exact integer)
  const int c = n >> 8, w = n >> 6;
  int rank = shb[c];
  for (int k = c * 4; k < w; ++k) rank += __popcll(shp[k]);
  rank += __popcll(shp[w] & ((1ULL << (n & 63)) - 1ULL));
  // query row (idempotent duplicate writes of identical data)
  const float* p = pts + (size_t)n * 5;
  float* q = out_query + (size_t)rank * 5;
  q[0] = p[0]; q[1] = p[1]; q[2] = p[2]; q[3] = p[3]; q[4] = p[4];
  float* o = out_samp + (size_t)e * 5;
  if (s < kcount[m]) {
    o[0] = p[0]; o[1] = p[1]; o[2] = p[2]; o[3] = p[3]; o[4] = p[4];
    out_idx[e] = (float)rank;  // idx section read back as f32; exact
  } else {
    o[0] = 0.f; o[1] = 0.f; o[2] = 0.f; o[3] = 0.f; o[4] = 0.f;
    out_idx[e] = 0.f;
  }
}

extern "C" void kernel_launch(void* const* d_in, const int* in_sizes, int n_in,
                              void* d_out, int out_size, void* d_ws, size_t ws_size,
                              hipStream_t stream) {
  const float* pts = (const float*)d_in[0];
  const float* boxes = (const float*)d_in[1];
  const float* pc_start = (const float*)d_in[2];
  const int N = in_sizes[0] / 5;
  const int M = in_sizes[1] / 7;
  const int S = out_size / (M * 11);   // out = M*S*5 + M*S + M*S*5
  const int MS = M * S;

  float* out_samp = (float*)d_out;
  float* out_idx = out_samp + (size_t)MS * 5;
  float* out_query = out_idx + (size_t)MS;

  const int nb = (N + 255) / 256;   // = nchunk; 782 for N=200000 (<=1024 for scans)
  const int nchunk = nb;

  // workspace layout (16B-aligned slices)
  char* w = (char*)d_ws;
  auto take = [&](size_t bytes) {
    char* p = w;
    w += (bytes + 15) & ~(size_t)15;
    return (void*)p;
  };
  u64* vbits     = (u64*)take((size_t)(nb * 4) * 8);
  u64* bmG       = (u64*)take((size_t)nchunk * M * 4 * 8);
  int* cpng      = (int*)take((size_t)nchunk * 256 * 4);
  int* sidx      = (int*)take((size_t)MS * 4);
  int* kcount    = (int*)take((size_t)M * 4);
  u8*  present   = (u8*)take((size_t)N);
  float* qxv     = (float*)take((size_t)M * 4);
  float* qyv     = (float*)take((size_t)M * 4);
  float* rv      = (float*)take((size_t)M * 4);
  int* cellCnt   = (int*)take((size_t)NCX * NCX * 4);
  u16* cellList  = (u16*)take((size_t)NCX * NCX * CAP * 2);

  k_prep<<<NCX * NCX + 1, 256, 0, stream>>>(boxes, pc_start, qxv, qyv, rv,
                                            cellCnt, cellList, M);
  k_vmask_count<<<nb, 256, 0, stream>>>(pts, boxes, qxv, qyv, rv, cellCnt, cellList,
                                        vbits, present, bmG, cpng, pc_start, N, M);
  k_scanfill<<<M, 1024, 0, stream>>>(pts, boxes, bmG, cpng, vbits, kcount,
                                     sidx, present, N, M, S, nchunk);
  k_out<<<(MS + 1023) / 1024, 1024, 0, stream>>>(pts, sidx, kcount, present,
                                                 out_samp, out_idx, out_query,
                                                 N, MS, S, nchunk);
}

// Round 15
// 88.891 us; speedup vs baseline: 1.7386x; 1.7386x over previous
//
#include <hip/hip_runtime.h>

typedef unsigned long long u64;
typedef unsigned int u32;
typedef unsigned short u16;
typedef unsigned char u8;

#define VOX 0.4f
#define GAM 1.1f
#define NCX 16        // 16x16 cells
#define CELLW 32.0f   // voxels per cell (power of 2: floor(pvx/32) exact)
#define CAP 64        // max candidate boxes per cell (sentinel fallback if exceeded)

// IEEE f32, no contraction: replicate numpy/jax op-for-op.
__device__ __forceinline__ float dist2d(float ax, float ay, float bx, float by) {
  float dx = __fsub_rn(ax, bx);
  float dy = __fsub_rn(ay, by);
  return __fsqrt_rn(__fadd_rn(__fmul_rn(dx, dx), __fmul_rn(dy, dy)));
}

// metric radius = norm(dims*0.5) * GAMMA
__device__ __forceinline__ float box_radius(const float* __restrict__ boxes, int m) {
  float hx = __fmul_rn(boxes[m * 7 + 3], 0.5f);
  float hy = __fmul_rn(boxes[m * 7 + 4], 0.5f);
  float nr = __fsqrt_rn(__fadd_rn(__fmul_rn(hx, hx), __fmul_rn(hy, hy)));
  return __fmul_rn(nr, GAM);
}

// voxel-space box transform (shared so values are identical everywhere)
__device__ __forceinline__ void box_voxel(const float* __restrict__ boxes, int m,
                                          float psx, float psy,
                                          float& qx, float& qy, float& r) {
  qx = __fdiv_rn(__fsub_rn(boxes[m * 7 + 0], psx), VOX);
  qy = __fdiv_rn(__fsub_rn(boxes[m * 7 + 1], psy), VOX);
  float hx = __fmul_rn(boxes[m * 7 + 3], 0.5f);
  float hy = __fmul_rn(boxes[m * 7 + 4], 0.5f);
  float nr = __fsqrt_rn(__fadd_rn(__fmul_rn(hx, hx), __fmul_rn(hy, hy)));
  r = __fdiv_rn(__fmul_rn(nr, GAM), VOX);
}

// ---- merged prep: block 0 -> voxel box arrays; blocks 1.. -> cell candidate lists
__global__ void k_prep(const float* __restrict__ boxes, const float* __restrict__ pc_start,
                       float* __restrict__ qxv, float* __restrict__ qyv, float* __restrict__ rv,
                       int* __restrict__ cellCnt, u16* __restrict__ cellList, int M) {
  const int tid = threadIdx.x;
  if (blockIdx.x == 0) {
    for (int m = tid; m < M; m += 256) {
      float qx, qy, r;
      box_voxel(boxes, m, pc_start[0], pc_start[1], qx, qy, r);
      qxv[m] = qx; qyv[m] = qy; rv[m] = r;
    }
    return;
  }
  const int cell = blockIdx.x - 1;
  const int cx = cell & (NCX - 1), cy = cell >> 4;
  const int wv = tid >> 6, lane = tid & 63;
  __shared__ int wcnt[4];
  const float x0 = (cx == 0) ? -3e38f : cx * CELLW;
  const float x1 = (cx == NCX - 1) ? 3e38f : (cx + 1) * CELLW;
  const float y0 = (cy == 0) ? -3e38f : cy * CELLW;
  const float y1 = (cy == NCX - 1) ? 3e38f : (cy + 1) * CELLW;
  bool hit = false;
  if (tid < M) {
    float qx, qy, r;
    box_voxel(boxes, tid, pc_start[0], pc_start[1], qx, qy, r);
    float ddx = fmaxf(0.0f, fmaxf(x0 - qx, qx - x1));
    float ddy = fmaxf(0.0f, fmaxf(y0 - qy, qy - y1));
    float rr = r + 0.01f;  // conservative margin >> f32 rounding of exact test chain
    hit = (ddx * ddx + ddy * ddy <= rr * rr);
  }
  u64 b = __ballot(hit);
  if (lane == 0) wcnt[wv] = __popcll(b);
  __syncthreads();
  int base = 0;
  for (int w = 0; w < wv; ++w) base += wcnt[w];
  if (hit) {
    int slot = base + __popcll(b & ((1ULL << lane) - 1ULL));
    if (slot < CAP) cellList[cell * CAP + slot] = (u16)tid;  // ascending m
  }
  if (tid == 0) cellCnt[cell] = wcnt[0] + wcnt[1] + wcnt[2] + wcnt[3];
}

// ---- fused: binned vmask (strict <) + ORDERED compaction + per-(chunk,box) match
//      BITMAP via point-centric candidate tests. chunk == one block == 256 points.
//      bmG layout: [chunk][m][4] -> coalesced dump writes.
__global__ void k_vmask_count(const float* __restrict__ pts, const float* __restrict__ boxes,
                              const float* __restrict__ qxv, const float* __restrict__ qyv,
                              const float* __restrict__ rv,
                              const int* __restrict__ cellCnt, const u16* __restrict__ cellList,
                              u64* __restrict__ vbits, u64* __restrict__ pbits,
                              u64* __restrict__ bmG, int* __restrict__ cpng,
                              const float* __restrict__ pc_start,
                              int N, int M) {
  __shared__ float cpx[256], cpy[256];          // compacted flagged points (metric xy)
  __shared__ int cpn[256];                      // compacted point indices
  __shared__ int ccell[256];                    // compacted point cell ids
  __shared__ float sbx[256], sby[256], sbr[256];// metric box centers/radii
  __shared__ u64 bm[256][4];                    // per-box match bitmap over 256 slots
  __shared__ int wcnt[4];
  const int tid = threadIdx.x;
  const int blk = blockIdx.x;
  const int n = blk * 256 + tid;
  const int wv = tid >> 6, lane = tid & 63;
  const float psx = pc_start[0], psy = pc_start[1];
  const bool valid = (n < N);

  bm[tid][0] = 0; bm[tid][1] = 0; bm[tid][2] = 0; bm[tid][3] = 0;
  if (tid < 4) pbits[blk * 4 + tid] = 0;  // zero presence bitmap (25KB total)
  if (tid < M) {
    sbx[tid] = boxes[tid * 7 + 0];
    sby[tid] = boxes[tid * 7 + 1];
    sbr[tid] = box_radius(boxes, tid);
  }

  float px = 1e6f, py = 1e6f, pvx = 0.f, pvy = 0.f;
  if (valid) {
    px = pts[n * 5 + 0];
    py = pts[n * 5 + 1];
    pvx = __fdiv_rn(__fsub_rn(px, psx), VOX);
    pvy = __fdiv_rn(__fsub_rn(py, psy), VOX);
  }

  // pass 1: vmask via candidate cells; identical IEEE ops as full loop
  bool flag = false;
  int mycell = 0;
  if (valid) {
    int cx = (int)floorf(pvx * (1.0f / CELLW));  // exact: /32 power of two
    int cy = (int)floorf(pvy * (1.0f / CELLW));
    cx = cx < 0 ? 0 : (cx > NCX - 1 ? NCX - 1 : cx);
    cy = cy < 0 ? 0 : (cy > NCX - 1 ? NCX - 1 : cy);
    mycell = cy * NCX + cx;
    const int k = cellCnt[mycell];
    if (k <= CAP) {
      for (int j = 0; j < k; ++j) {
        const int m = cellList[mycell * CAP + j];
        float d = dist2d(qxv[m], qyv[m], pvx, pvy);
        if (d < rv[m]) { flag = true; break; }  // strict <
      }
    } else {  // sentinel fallback (dormant for this data)
      for (int m = 0; m < M; ++m) {
        float d = dist2d(qxv[m], qyv[m], pvx, pvy);
        if (d < rv[m]) { flag = true; break; }
      }
    }
  }
  u64 b = __ballot(flag);
  if (lane == 0) {
    vbits[n >> 6] = b;
    wcnt[wv] = __popcll(b);
  }
  __syncthreads();

  // ORDERED compaction (ascending n) of flagged points into LDS
  int base = 0;
  for (int w = 0; w < wv; ++w) base += wcnt[w];
  if (flag) {
    int slot = base + __popcll(b & ((1ULL << lane) - 1ULL));
    cpx[slot] = px;
    cpy[slot] = py;
    cpn[slot] = n;
    ccell[slot] = mycell;
  }
  __syncthreads();
  const int nfl = wcnt[0] + wcnt[1] + wcnt[2] + wcnt[3];
  if (tid < nfl) cpng[blk * 256 + tid] = cpn[tid];

  // pass 2: point-centric metric tests against the point's cell candidates.
  // Exact: metric match d<=r implies voxel dist <= rv + ~1e-4 << 0.01 margin,
  // so the candidate list provably contains every metric-matching box.
  if (tid < nfl) {
    const float mx = cpx[tid], my = cpy[tid];
    const int cell = ccell[tid];
    const int k = cellCnt[cell];
    const u64 bit = 1ULL << (tid & 63);
    const int word = tid >> 6;
    if (k <= CAP) {
      for (int j = 0; j < k; ++j) {
        const int m = cellList[cell * CAP + j];
        float d = dist2d(sbx[m], sby[m], mx, my);
        if (d <= sbr[m]) atomicOr(&bm[m][word], bit);  // metric space, <= (LDS atomic)
      }
    } else {  // fallback: test all boxes (dormant)
      for (int m = 0; m < M; ++m) {
        float d = dist2d(sbx[m], sby[m], mx, my);
        if (d <= sbr[m]) atomicOr(&bm[m][word], bit);
      }
    }
  }
  __syncthreads();

  // dump bitmap (thread = box; [chunk][m] layout -> coalesced 8KB block write)
  if (tid < M) {
    u64* dst = bmG + ((size_t)blk * M + tid) * 4;
    dst[0] = bm[tid][0]; dst[1] = bm[tid][1];
    dst[2] = bm[tid][2]; dst[3] = bm[tid][3];
  }
}

// ---- fused per-box scan + bitmap fill + wide zero-fill. block = box, 1024 thr.
//      presence recorded in pbits via WAVE-AGGREGATED atomics (R11 lesson).
__global__ void __launch_bounds__(1024) k_scanfill(
    const float* __restrict__ pts, const float* __restrict__ boxes,
    const u64* __restrict__ bmG, const int* __restrict__ cpng,
    const u64* __restrict__ vbits, int* __restrict__ kcount,
    int* __restrict__ sidx, u64* __restrict__ pbits,
    int N, int M, int S, int nchunk) {
  const int m = blockIdx.x;
  const int t = threadIdx.x;
  const int lane = t & 63, wv = t >> 6;  // 16 waves
  __shared__ int wsum[16];
  __shared__ int zws[16];

  // load my chunk's bitmap (thread t = chunk t; nchunk <= 1024)
  u64 w0 = 0, w1 = 0, w2 = 0, w3 = 0;
  int v = 0;
  if (t < nchunk) {
    const u64* bp = bmG + ((size_t)t * M + m) * 4;
    w0 = bp[0]; w1 = bp[1]; w2 = bp[2]; w3 = bp[3];
    v = __popcll(w0) + __popcll(w1) + __popcll(w2) + __popcll(w3);
  }
  // inclusive wave-shfl scan
  int incl = v;
  for (int d = 1; d < 64; d <<= 1) {
    int x = __shfl_up(incl, d);
    if (lane >= d) incl += x;
  }
  if (lane == 63) wsum[wv] = incl;
  __syncthreads();
  if (t < 16) {  // scan the 16 wave sums (lanes 0-15 of wave 0)
    int s = wsum[t];
    for (int d = 1; d < 16; d <<= 1) {
      int x = __shfl_up(s, d);
      if (t >= d) s += x;
    }
    wsum[t] = s;  // inclusive
  }
  __syncthreads();
  const int wbase = (wv > 0) ? wsum[wv - 1] : 0;
  const int off = wbase + incl - v;  // exclusive prefix over chunks
  const int total = wsum[15];
  const int k0 = total < S ? total : S;
  if (t == 0) kcount[m] = k0;

  // fill from bitmap (ascending slot = ascending point index).
  // pn ascending -> word index non-decreasing -> local accumulate, <=5 flushes.
  if (t < nchunk && v > 0 && off < S) {
    const int* pbase = cpng + t * 256;
    int cum = off;
    int curw = -1;
    u64 acc = 0;
    u64 ws4[4] = {w0, w1, w2, w3};
    for (int wi = 0; wi < 4 && cum < S; ++wi) {
      u64 w = ws4[wi];
      while (w && cum < S) {
        int j = (wi << 6) + __builtin_ctzll(w);
        w &= w - 1;
        int pn = pbase[j];
        sidx[m * S + cum] = pn;
        const int wd = pn >> 6;
        if (wd != curw) {
          if (curw >= 0) atomicOr(&pbits[curw], acc);
          curw = wd;
          acc = 0;
        }
        acc |= 1ULL << (pn & 63);
        ++cum;
      }
    }
    if (curw >= 0) atomicOr(&pbits[curw], acc);
  }

  // zero-fill: lowest-index non-matches (top_k tie-break among zeros).
  // A wave's 64 lanes cover ONE aligned u64 word -> one ballot-aggregated atomicOr.
  if (k0 >= S) return;  // uniform per block -> barrier-safe
  const float bx = boxes[m * 7 + 0], by = boxes[m * 7 + 1];
  const float r = box_radius(boxes, m);
  const u64 ltmask = (1ULL << lane) - 1ULL;
  int fill = k0;
  for (int p0 = 0; p0 < N && fill < S; p0 += 1024) {
    const int n = p0 + t;
    const bool validn = n < N;
    bool one = false;
    if (validn) {
      u64 wbit = vbits[n >> 6];  // one word per wave (broadcast)
      if ((wbit >> (n & 63)) & 1ULL) {
        float d = dist2d(bx, by, pts[n * 5 + 0], pts[n * 5 + 1]);
        one = (d <= r);
      }
    }
    const bool z = validn && !one;
    u64 b = __ballot(z);
    if (lane == 0) zws[wv] = __popcll(b);
    __syncthreads();
    int zbase = 0, ztot = 0;
    for (int ww = 0; ww < 16; ++ww) {
      int c = zws[ww];
      if (ww < wv) zbase += c;
      ztot += c;
    }
    bool setp = false;
    if (z) {
      int pos = fill + zbase + __popcll(b & ltmask);
      if (pos < S) { sidx[m * S + pos] = n; setp = true; }
    }
    u64 setmask = __ballot(setp);
    if (lane == 0 && setmask) atomicOr(&pbits[n >> 6], setmask);  // 1 atomic/wave
    fill += ztot;
    __syncthreads();
  }
}

// ---- presence-bitmap popcount + exclusive scan (one block; reads only 25KB) ----
__global__ void __launch_bounds__(1024) k_sumscan(const u64* __restrict__ pbits,
                                                  int* __restrict__ boff, int nb) {
  __shared__ int wsum[16];
  const int t = threadIdx.x, lane = t & 63, wv = t >> 6;
  int v = 0;
  if (t < nb) {
    const u64* p = pbits + (size_t)t * 4;  // 32B per thread, coalesced
    v = __popcll(p[0]) + __popcll(p[1]) + __popcll(p[2]) + __popcll(p[3]);
  }
  int incl = v;
  for (int d = 1; d < 64; d <<= 1) {
    int x = __shfl_up(incl, d);
    if (lane >= d) incl += x;
  }
  if (lane == 63) wsum[wv] = incl;
  __syncthreads();
  if (t < 16) {
    int s = wsum[t];
    for (int d = 1; d < 16; d <<= 1) {
      int x = __shfl_up(s, d);
      if (t >= d) s += x;
    }
    wsum[t] = s;
  }
  __syncthreads();
  const int base = (wv > 0) ? wsum[wv - 1] : 0;
  if (t < nb) boff[t] = base + incl - v;  // exclusive per-chunk presence offset
  if (t == 0) boff[1024] = wsum[15];      // U = total unique count
}

// --- merged outputs: sampled + idx (rank computed inline from pbits) + query + pad
__global__ void k_outpad(const float* __restrict__ pts, const int* __restrict__ sidx,
                         const int* __restrict__ kcount, const u64* __restrict__ pbits,
                         const int* __restrict__ boff,
                         float* __restrict__ out_samp, float* __restrict__ out_idx,
                         float* __restrict__ out_query, int MS, int S) {
  const int e = blockIdx.x * 256 + threadIdx.x;
  if (e >= MS) return;
  const int U = boff[1024];
  if (e >= U) {  // pad query rows with points[0] (unique fill_value=0)
    float* q = out_query + (size_t)e * 5;
    q[0] = pts[0]; q[1] = pts[1]; q[2] = pts[2]; q[3] = pts[3]; q[4] = pts[4];
  }
  const int m = e / S;
  const int s = e - m * S;
  const int n = sidx[e];  // valid for ALL slots (fill or zero-fill wrote it)
  // rank(n) = boff[chunk] + popcount of pbits bits below n (exact integer)
  const int c = n >> 8, w = n >> 6;
  int rank = boff[c];
  for (int k = c * 4; k < w; ++k) rank += __popcll(pbits[k]);
  rank += __popcll(pbits[w] & ((1ULL << (n & 63)) - 1ULL));
  // query row (idempotent duplicate writes of identical data)
  const float* p = pts + (size_t)n * 5;
  float* q = out_query + (size_t)rank * 5;
  q[0] = p[0]; q[1] = p[1]; q[2] = p[2]; q[3] = p[3]; q[4] = p[4];
  float* o = out_samp + (size_t)e * 5;
  if (s < kcount[m]) {
    o[0] = p[0]; o[1] = p[1]; o[2] = p[2]; o[3] = p[3]; o[4] = p[4];
    out_idx[e] = (float)rank;  // idx section read back as f32; exact
  } else {
    o[0] = 0.f; o[1] = 0.f; o[2] = 0.f; o[3] = 0.f; o[4] = 0.f;
    out_idx[e] = 0.f;
  }
}

extern "C" void kernel_launch(void* const* d_in, const int* in_sizes, int n_in,
                              void* d_out, int out_size, void* d_ws, size_t ws_size,
                              hipStream_t stream) {
  const float* pts = (const float*)d_in[0];
  const float* boxes = (const float*)d_in[1];
  const float* pc_start = (const float*)d_in[2];
  const int N = in_sizes[0] / 5;
  const int M = in_sizes[1] / 7;
  const int S = out_size / (M * 11);   // out = M*S*5 + M*S + M*S*5
  const int MS = M * S;

  float* out_samp = (float*)d_out;
  float* out_idx = out_samp + (size_t)MS * 5;
  float* out_query = out_idx + (size_t)MS;

  const int nb = (N + 255) / 256;   // = nchunk; 782 for N=200000 (<=1024 for scans)
  const int nchunk = nb;

  // workspace layout (16B-aligned slices)
  char* w = (char*)d_ws;
  auto take = [&](size_t bytes) {
    char* p = w;
    w += (bytes + 15) & ~(size_t)15;
    return (void*)p;
  };
  u64* vbits     = (u64*)take((size_t)(nb * 4) * 8);
  u64* pbits     = (u64*)take((size_t)(nb * 4) * 8);
  u64* bmG       = (u64*)take((size_t)nchunk * M * 4 * 8);
  int* cpng      = (int*)take((size_t)nchunk * 256 * 4);
  int* sidx      = (int*)take((size_t)MS * 4);
  int* kcount    = (int*)take((size_t)M * 4);
  int* boff      = (int*)take((size_t)1025 * 4);
  float* qxv     = (float*)take((size_t)M * 4);
  float* qyv     = (float*)take((size_t)M * 4);
  float* rv      = (float*)take((size_t)M * 4);
  int* cellCnt   = (int*)take((size_t)NCX * NCX * 4);
  u16* cellList  = (u16*)take((size_t)NCX * NCX * CAP * 2);

  k_prep<<<NCX * NCX + 1, 256, 0, stream>>>(boxes, pc_start, qxv, qyv, rv,
                                            cellCnt, cellList, M);
  k_vmask_count<<<nb, 256, 0, stream>>>(pts, boxes, qxv, qyv, rv, cellCnt, cellList,
                                        vbits, pbits, bmG, cpng, pc_start, N, M);
  k_scanfill<<<M, 1024, 0, stream>>>(pts, boxes, bmG, cpng, vbits, kcount,
                                     sidx, pbits, N, M, S, nchunk);
  k_sumscan<<<1, 1024, 0, stream>>>(pbits, boff, nb);
  k_outpad<<<(MS + 255) / 256, 256, 0, stream>>>(pts, sidx, kcount, pbits, boff,
                                                 out_samp, out_idx, out_query, MS, S);
}

// Round 16
// 87.857 us; speedup vs baseline: 1.7590x; 1.0118x over previous
//
#include <hip/hip_runtime.h>

typedef unsigned long long u64;
typedef unsigned int u32;
typedef unsigned short u16;
typedef unsigned char u8;

#define VOX 0.4f
#define GAM 1.1f
#define NCX 16        // 16x16 cells
#define CELLW 32.0f   // voxels per cell (power of 2: floor(pvx/32) exact)
#define CAP 64        // max candidate boxes per cell (sentinel fallback if exceeded)

// IEEE f32, no contraction: replicate numpy/jax op-for-op.
__device__ __forceinline__ float dist2d(float ax, float ay, float bx, float by) {
  float dx = __fsub_rn(ax, bx);
  float dy = __fsub_rn(ay, by);
  return __fsqrt_rn(__fadd_rn(__fmul_rn(dx, dx), __fmul_rn(dy, dy)));
}

// metric radius = norm(dims*0.5) * GAMMA
__device__ __forceinline__ float box_radius(const float* __restrict__ boxes, int m) {
  float hx = __fmul_rn(boxes[m * 7 + 3], 0.5f);
  float hy = __fmul_rn(boxes[m * 7 + 4], 0.5f);
  float nr = __fsqrt_rn(__fadd_rn(__fmul_rn(hx, hx), __fmul_rn(hy, hy)));
  return __fmul_rn(nr, GAM);
}

// voxel-space box transform (shared so values are identical everywhere)
__device__ __forceinline__ void box_voxel(const float* __restrict__ boxes, int m,
                                          float psx, float psy,
                                          float& qx, float& qy, float& r) {
  qx = __fdiv_rn(__fsub_rn(boxes[m * 7 + 0], psx), VOX);
  qy = __fdiv_rn(__fsub_rn(boxes[m * 7 + 1], psy), VOX);
  float hx = __fmul_rn(boxes[m * 7 + 3], 0.5f);
  float hy = __fmul_rn(boxes[m * 7 + 4], 0.5f);
  float nr = __fsqrt_rn(__fadd_rn(__fmul_rn(hx, hx), __fmul_rn(hy, hy)));
  r = __fdiv_rn(__fmul_rn(nr, GAM), VOX);
}

// ---- prep: block = cell; conservative cell->box candidate lists ----
__global__ void k_prep(const float* __restrict__ boxes, const float* __restrict__ pc_start,
                       int* __restrict__ cellCnt, u16* __restrict__ cellList, int M) {
  const int cell = blockIdx.x;
  const int cx = cell & (NCX - 1), cy = cell >> 4;
  const int tid = threadIdx.x;
  const int wv = tid >> 6, lane = tid & 63;
  __shared__ int wcnt[4];
  const float x0 = (cx == 0) ? -3e38f : cx * CELLW;
  const float x1 = (cx == NCX - 1) ? 3e38f : (cx + 1) * CELLW;
  const float y0 = (cy == 0) ? -3e38f : cy * CELLW;
  const float y1 = (cy == NCX - 1) ? 3e38f : (cy + 1) * CELLW;
  bool hit = false;
  if (tid < M) {
    float qx, qy, r;
    box_voxel(boxes, tid, pc_start[0], pc_start[1], qx, qy, r);
    float ddx = fmaxf(0.0f, fmaxf(x0 - qx, qx - x1));
    float ddy = fmaxf(0.0f, fmaxf(y0 - qy, qy - y1));
    float rr = r + 0.01f;  // conservative margin >> f32 rounding of exact test chain
    hit = (ddx * ddx + ddy * ddy <= rr * rr);
  }
  u64 b = __ballot(hit);
  if (lane == 0) wcnt[wv] = __popcll(b);
  __syncthreads();
  int base = 0;
  for (int w = 0; w < wv; ++w) base += wcnt[w];
  if (hit) {
    int slot = base + __popcll(b & ((1ULL << lane) - 1ULL));
    if (slot < CAP) cellList[cell * CAP + slot] = (u16)tid;  // ascending m
  }
  if (tid == 0) cellCnt[cell] = wcnt[0] + wcnt[1] + wcnt[2] + wcnt[3];
}

// ---- fused: binned vmask (strict <) + ORDERED compaction + per-(chunk,box) match
//      BITMAP via point-centric candidate tests. chunk == one block == 256 points.
//      All box data (voxel + metric) staged in LDS; bmG layout [chunk][m][4].
__global__ void k_vmask_count(const float* __restrict__ pts, const float* __restrict__ boxes,
                              const int* __restrict__ cellCnt, const u16* __restrict__ cellList,
                              u64* __restrict__ vbits, u64* __restrict__ pbits,
                              u64* __restrict__ bmG, int* __restrict__ cpng,
                              const float* __restrict__ pc_start,
                              int N, int M) {
  __shared__ float cpx[256], cpy[256];          // compacted flagged points (metric xy)
  __shared__ int cpn[256];                      // compacted point indices
  __shared__ int ccell[256];                    // compacted point cell ids
  __shared__ float sbx[256], sby[256], sbr[256];// metric box centers/radii
  __shared__ float sqx[256], sqy[256], srv[256];// voxel box centers/radii
  __shared__ u64 bm[256][4];                    // per-box match bitmap over 256 slots
  __shared__ int wcnt[4];
  const int tid = threadIdx.x;
  const int blk = blockIdx.x;
  const int n = blk * 256 + tid;
  const int wv = tid >> 6, lane = tid & 63;
  const float psx = pc_start[0], psy = pc_start[1];
  const bool valid = (n < N);

  bm[tid][0] = 0; bm[tid][1] = 0; bm[tid][2] = 0; bm[tid][3] = 0;
  if (tid < 4) pbits[blk * 4 + tid] = 0;  // zero presence bitmap (25KB total)
  if (tid < M) {
    sbx[tid] = boxes[tid * 7 + 0];
    sby[tid] = boxes[tid * 7 + 1];
    sbr[tid] = box_radius(boxes, tid);
    float qx, qy, r;
    box_voxel(boxes, tid, psx, psy, qx, qy, r);  // identical IEEE chain as k_prep
    sqx[tid] = qx; sqy[tid] = qy; srv[tid] = r;
  }

  float px = 1e6f, py = 1e6f, pvx = 0.f, pvy = 0.f;
  if (valid) {
    px = pts[n * 5 + 0];
    py = pts[n * 5 + 1];
    pvx = __fdiv_rn(__fsub_rn(px, psx), VOX);
    pvy = __fdiv_rn(__fsub_rn(py, psy), VOX);
  }
  __syncthreads();  // LDS box arrays ready

  // pass 1: vmask via candidate cells; identical IEEE ops as full loop
  bool flag = false;
  int mycell = 0;
  if (valid) {
    int cx = (int)floorf(pvx * (1.0f / CELLW));  // exact: /32 power of two
    int cy = (int)floorf(pvy * (1.0f / CELLW));
    cx = cx < 0 ? 0 : (cx > NCX - 1 ? NCX - 1 : cx);
    cy = cy < 0 ? 0 : (cy > NCX - 1 ? NCX - 1 : cy);
    mycell = cy * NCX + cx;
    const int k = cellCnt[mycell];
    if (k <= CAP) {
      for (int j = 0; j < k; ++j) {
        const int m = cellList[mycell * CAP + j];
        float d = dist2d(sqx[m], sqy[m], pvx, pvy);
        if (d < srv[m]) { flag = true; break; }  // strict <
      }
    } else {  // sentinel fallback (dormant for this data)
      for (int m = 0; m < M; ++m) {
        float d = dist2d(sqx[m], sqy[m], pvx, pvy);
        if (d < srv[m]) { flag = true; break; }
      }
    }
  }
  u64 b = __ballot(flag);
  if (lane == 0) {
    vbits[n >> 6] = b;
    wcnt[wv] = __popcll(b);
  }
  __syncthreads();

  // ORDERED compaction (ascending n) of flagged points into LDS
  int base = 0;
  for (int w = 0; w < wv; ++w) base += wcnt[w];
  if (flag) {
    int slot = base + __popcll(b & ((1ULL << lane) - 1ULL));
    cpx[slot] = px;
    cpy[slot] = py;
    cpn[slot] = n;
    ccell[slot] = mycell;
  }
  __syncthreads();
  const int nfl = wcnt[0] + wcnt[1] + wcnt[2] + wcnt[3];
  if (tid < nfl) cpng[blk * 256 + tid] = cpn[tid];

  // pass 2: point-centric metric tests against the point's cell candidates.
  // Exact: metric match d<=r implies voxel dist <= rv + ~1e-4 << 0.01 margin,
  // so the candidate list provably contains every metric-matching box.
  if (tid < nfl) {
    const float mx = cpx[tid], my = cpy[tid];
    const int cell = ccell[tid];
    const int k = cellCnt[cell];
    const u64 bit = 1ULL << (tid & 63);
    const int word = tid >> 6;
    if (k <= CAP) {
      for (int j = 0; j < k; ++j) {
        const int m = cellList[cell * CAP + j];
        float d = dist2d(sbx[m], sby[m], mx, my);
        if (d <= sbr[m]) atomicOr(&bm[m][word], bit);  // metric space, <= (LDS atomic)
      }
    } else {  // fallback: test all boxes (dormant)
      for (int m = 0; m < M; ++m) {
        float d = dist2d(sbx[m], sby[m], mx, my);
        if (d <= sbr[m]) atomicOr(&bm[m][word], bit);
      }
    }
  }
  __syncthreads();

  // dump bitmap (thread = box; [chunk][m] layout -> coalesced 8KB block write)
  if (tid < M) {
    u64* dst = bmG + ((size_t)blk * M + tid) * 4;
    dst[0] = bm[tid][0]; dst[1] = bm[tid][1];
    dst[2] = bm[tid][2]; dst[3] = bm[tid][3];
  }
}

// ---- fused per-box scan + bitmap fill + wide zero-fill. block = box, 1024 thr.
//      presence recorded in pbits via WAVE-AGGREGATED atomics (R11 lesson).
__global__ void __launch_bounds__(1024) k_scanfill(
    const float* __restrict__ pts, const float* __restrict__ boxes,
    const u64* __restrict__ bmG, const int* __restrict__ cpng,
    const u64* __restrict__ vbits, int* __restrict__ kcount,
    int* __restrict__ sidx, u64* __restrict__ pbits,
    int N, int M, int S, int nchunk) {
  const int m = blockIdx.x;
  const int t = threadIdx.x;
  const int lane = t & 63, wv = t >> 6;  // 16 waves
  __shared__ int wsum[16];
  __shared__ int zws[16];

  // load my chunk's bitmap (thread t = chunk t; nchunk <= 1024)
  u64 w0 = 0, w1 = 0, w2 = 0, w3 = 0;
  int v = 0;
  if (t < nchunk) {
    const u64* bp = bmG + ((size_t)t * M + m) * 4;
    w0 = bp[0]; w1 = bp[1]; w2 = bp[2]; w3 = bp[3];
    v = __popcll(w0) + __popcll(w1) + __popcll(w2) + __popcll(w3);
  }
  // inclusive wave-shfl scan
  int incl = v;
  for (int d = 1; d < 64; d <<= 1) {
    int x = __shfl_up(incl, d);
    if (lane >= d) incl += x;
  }
  if (lane == 63) wsum[wv] = incl;
  __syncthreads();
  if (t < 16) {  // scan the 16 wave sums (lanes 0-15 of wave 0)
    int s = wsum[t];
    for (int d = 1; d < 16; d <<= 1) {
      int x = __shfl_up(s, d);
      if (t >= d) s += x;
    }
    wsum[t] = s;  // inclusive
  }
  __syncthreads();
  const int wbase = (wv > 0) ? wsum[wv - 1] : 0;
  const int off = wbase + incl - v;  // exclusive prefix over chunks
  const int total = wsum[15];
  const int k0 = total < S ? total : S;
  if (t == 0) kcount[m] = k0;

  // fill from bitmap (ascending slot = ascending point index).
  // pn ascending -> word index non-decreasing -> local accumulate, <=5 flushes.
  if (t < nchunk && v > 0 && off < S) {
    const int* pbase = cpng + t * 256;
    int cum = off;
    int curw = -1;
    u64 acc = 0;
    u64 ws4[4] = {w0, w1, w2, w3};
    for (int wi = 0; wi < 4 && cum < S; ++wi) {
      u64 w = ws4[wi];
      while (w && cum < S) {
        int j = (wi << 6) + __builtin_ctzll(w);
        w &= w - 1;
        int pn = pbase[j];
        sidx[m * S + cum] = pn;
        const int wd = pn >> 6;
        if (wd != curw) {
          if (curw >= 0) atomicOr(&pbits[curw], acc);
          curw = wd;
          acc = 0;
        }
        acc |= 1ULL << (pn & 63);
        ++cum;
      }
    }
    if (curw >= 0) atomicOr(&pbits[curw], acc);
  }

  // zero-fill: lowest-index non-matches (top_k tie-break among zeros).
  // A wave's 64 lanes cover ONE aligned u64 word -> one ballot-aggregated atomicOr.
  if (k0 >= S) return;  // uniform per block -> barrier-safe
  const float bx = boxes[m * 7 + 0], by = boxes[m * 7 + 1];
  const float r = box_radius(boxes, m);
  const u64 ltmask = (1ULL << lane) - 1ULL;
  int fill = k0;
  for (int p0 = 0; p0 < N && fill < S; p0 += 1024) {
    const int n = p0 + t;
    const bool validn = n < N;
    bool one = false;
    if (validn) {
      u64 wbit = vbits[n >> 6];  // one word per wave (broadcast)
      if ((wbit >> (n & 63)) & 1ULL) {
        float d = dist2d(bx, by, pts[n * 5 + 0], pts[n * 5 + 1]);
        one = (d <= r);
      }
    }
    const bool z = validn && !one;
    u64 b = __ballot(z);
    if (lane == 0) zws[wv] = __popcll(b);
    __syncthreads();
    int zbase = 0, ztot = 0;
    for (int ww = 0; ww < 16; ++ww) {
      int c = zws[ww];
      if (ww < wv) zbase += c;
      ztot += c;
    }
    bool setp = false;
    if (z) {
      int pos = fill + zbase + __popcll(b & ltmask);
      if (pos < S) { sidx[m * S + pos] = n; setp = true; }
    }
    u64 setmask = __ballot(setp);
    if (lane == 0 && setmask) atomicOr(&pbits[n >> 6], setmask);  // 1 atomic/wave
    fill += ztot;
    __syncthreads();
  }
}

// --- fused outputs: per-block replicated pbits-scan (25KB coalesced read) + outputs.
//     32 blocks x 1024 threads; each block popcounts pbits + 2-level shfl scan in
//     LDS (validated pattern), then emits its 1024 elements with inline rank.
__global__ void __launch_bounds__(1024) k_outpad(
    const float* __restrict__ pts, const int* __restrict__ sidx,
    const int* __restrict__ kcount, const u64* __restrict__ pbits,
    float* __restrict__ out_samp, float* __restrict__ out_idx,
    float* __restrict__ out_query, int MS, int S, int nchunk) {
  __shared__ int shb[1024];   // per-chunk exclusive presence offsets
  __shared__ int wsum[16];
  const int t = threadIdx.x, lane = t & 63, wv = t >> 6;

  // replicated sumscan: thread t popcounts chunk t's 4 u64 (32B coalesced)
  int v = 0;
  if (t < nchunk) {
    const u64* p = pbits + (size_t)t * 4;
    v = __popcll(p[0]) + __popcll(p[1]) + __popcll(p[2]) + __popcll(p[3]);
  }
  int incl = v;
  for (int d = 1; d < 64; d <<= 1) {
    int x = __shfl_up(incl, d);
    if (lane >= d) incl += x;
  }
  if (lane == 63) wsum[wv] = incl;
  __syncthreads();
  if (t < 16) {
    int s = wsum[t];
    for (int d = 1; d < 16; d <<= 1) {
      int x = __shfl_up(s, d);
      if (t >= d) s += x;
    }
    wsum[t] = s;
  }
  __syncthreads();
  shb[t] = ((wv > 0) ? wsum[wv - 1] : 0) + incl - v;  // exclusive
  const int U = wsum[15];
  __syncthreads();

  const int e = blockIdx.x * 1024 + t;
  if (e >= MS) return;
  if (e >= U) {  // pad query rows with points[0] (unique fill_value=0)
    float* q = out_query + (size_t)e * 5;
    q[0] = pts[0]; q[1] = pts[1]; q[2] = pts[2]; q[3] = pts[3]; q[4] = pts[4];
  }
  const int m = e / S;
  const int s = e - m * S;
  const int n = sidx[e];  // valid for ALL slots (fill or zero-fill wrote it)
  // rank(n) = shb[chunk] + popcount of pbits bits below n (exact integer)
  const int c = n >> 8, w = n >> 6;
  int rank = shb[c];
  for (int k = c * 4; k < w; ++k) rank += __popcll(pbits[k]);
  rank += __popcll(pbits[w] & ((1ULL << (n & 63)) - 1ULL));
  // query row (idempotent duplicate writes of identical data)
  const float* p = pts + (size_t)n * 5;
  float* q = out_query + (size_t)rank * 5;
  q[0] = p[0]; q[1] = p[1]; q[2] = p[2]; q[3] = p[3]; q[4] = p[4];
  float* o = out_samp + (size_t)e * 5;
  if (s < kcount[m]) {
    o[0] = p[0]; o[1] = p[1]; o[2] = p[2]; o[3] = p[3]; o[4] = p[4];
    out_idx[e] = (float)rank;  // idx section read back as f32; exact
  } else {
    o[0] = 0.f; o[1] = 0.f; o[2] = 0.f; o[3] = 0.f; o[4] = 0.f;
    out_idx[e] = 0.f;
  }
}

extern "C" void kernel_launch(void* const* d_in, const int* in_sizes, int n_in,
                              void* d_out, int out_size, void* d_ws, size_t ws_size,
                              hipStream_t stream) {
  const float* pts = (const float*)d_in[0];
  const float* boxes = (const float*)d_in[1];
  const float* pc_start = (const float*)d_in[2];
  const int N = in_sizes[0] / 5;
  const int M = in_sizes[1] / 7;
  const int S = out_size / (M * 11);   // out = M*S*5 + M*S + M*S*5
  const int MS = M * S;

  float* out_samp = (float*)d_out;
  float* out_idx = out_samp + (size_t)MS * 5;
  float* out_query = out_idx + (size_t)MS;

  const int nb = (N + 255) / 256;   // = nchunk; 782 for N=200000 (<=1024 for scans)
  const int nchunk = nb;

  // workspace layout (16B-aligned slices)
  char* w = (char*)d_ws;
  auto take = [&](size_t bytes) {
    char* p = w;
    w += (bytes + 15) & ~(size_t)15;
    return (void*)p;
  };
  u64* vbits     = (u64*)take((size_t)(nb * 4) * 8);
  u64* pbits     = (u64*)take((size_t)(nb * 4) * 8);
  u64* bmG       = (u64*)take((size_t)nchunk * M * 4 * 8);
  int* cpng      = (int*)take((size_t)nchunk * 256 * 4);
  int* sidx      = (int*)take((size_t)MS * 4);
  int* kcount    = (int*)take((size_t)M * 4);
  int* cellCnt   = (int*)take((size_t)NCX * NCX * 4);
  u16* cellList  = (u16*)take((size_t)NCX * NCX * CAP * 2);

  k_prep<<<NCX * NCX, 256, 0, stream>>>(boxes, pc_start, cellCnt, cellList, M);
  k_vmask_count<<<nb, 256, 0, stream>>>(pts, boxes, cellCnt, cellList,
                                        vbits, pbits, bmG, cpng, pc_start, N, M);
  k_scanfill<<<M, 1024, 0, stream>>>(pts, boxes, bmG, cpng, vbits, kcount,
                                     sidx, pbits, N, M, S, nchunk);
  k_outpad<<<(MS + 1023) / 1024, 1024, 0, stream>>>(pts, sidx, kcount, pbits,
                                                    out_samp, out_idx, out_query,
                                                    MS, S, nchunk);
}